// Round 6
// baseline (477.147 us; speedup 1.0000x reference)
//
#include <hip/hip_runtime.h>
#include <hip/hip_bf16.h>
#include <math.h>

#define N_NODES 40000
#define E_EDGES 60000
#define R_REL 6
#define IN_F 32
#define HID_F 128
#define B_GRAPHS 2000
#define NODES_PER_G 20
#define NEG_SLOPE 0.2f
#define NB (R_REL * N_NODES)            // 240000 bins
#define NTOT (R_REL * (E_EDGES + N_NODES))  // 600000 entries incl. self-loops
#define NBLK ((NB + 255) / 256)         // 938 scan blocks

// fused-prep block ranges
#define CNT_B ((NTOT + 255) / 256)          // 2344
#define CVT_B ((N_NODES * 16 + 255) / 256)  // 2500
#define P1_B  (R_REL * 512 * 32 / 256)      // 384
#define P2_B  (R_REL * 512 * 128 / 256)     // 1536
#define PREP_TOTAL (CNT_B + CVT_B + P1_B + P2_B + 1)

typedef __bf16 bf16x8 __attribute__((ext_vector_type(8)));
typedef float f32x4 __attribute__((ext_vector_type(4)));

__device__ __forceinline__ unsigned f2bfbits(float f) {
    unsigned u = __builtin_bit_cast(unsigned, f);
    return (u + 0x7FFFu + ((u >> 16) & 1u)) >> 16;   // RNE
}
__device__ __forceinline__ float bflo(unsigned u) { return __builtin_bit_cast(float, u << 16); }
__device__ __forceinline__ float bfhi(unsigned u) { return __builtin_bit_cast(float, u & 0xFFFF0000u); }

// tanh(x) = 1 - 2/(e^{2x}+1), via hw exp2 + fast rcp (~1e-6 rel, saturates to +-1)
__device__ __forceinline__ float fast_tanh(float x) {
    float e = __builtin_amdgcn_exp2f(x * 2.8853900817779268f);   // e^{2x}
    return fmaf(-2.f, __builtin_amdgcn_rcpf(e + 1.f), 1.f);
}

// DPP rotation add within row-16: pure VALU, no LDS pipe (verified r4/r5)
template<int CTRL>
__device__ __forceinline__ float dppadd(float v) {
    int m = __builtin_amdgcn_update_dpp(0, __builtin_bit_cast(int, v), CTRL, 0xF, 0xF, true);
    return v + __builtin_bit_cast(float, m);
}
__device__ __forceinline__ float rowsum16(float v) {   // all 16 lanes get row sum
    v = dppadd<0x121>(v);   // row_ror:1
    v = dppadd<0x122>(v);   // row_ror:2
    v = dppadd<0x124>(v);   // row_ror:4
    v = dppadd<0x128>(v);   // row_ror:8
    return v;
}
__device__ __forceinline__ float halfsum32(float v) {  // full sum within each 32-lane half
    v += __shfl_xor(v, 16);
    return rowsum16(v);
}

__device__ __forceinline__ void prep_w_body(
    const float* __restrict__ Wl, const float* __restrict__ Wr,
    const float* __restrict__ bl, const float* __restrict__ br,
    unsigned short* __restrict__ Bt, float* __restrict__ bcat, int K, int idx)
{
    if (idx >= R_REL * 512 * K) return;
    int k = idx % K;
    int rn = idx / K;
    int n = rn % 512;
    int r = rn / 512;
    int nn = n & 255;
    const float* W = (n < 256) ? Wl : Wr;
    float w = W[((size_t)r * K + k) * 256 + nn];
    Bt[idx] = (unsigned short)f2bfbits(w);
    if (k == 0)
        bcat[rn] = (n < 256) ? bl[r * 256 + nn] : br[r * 256 + nn];
}

// -------- fused prep: count + cvt + prep_w x2 + bias_sum + att-prescale -------
__global__ __launch_bounds__(256) void fused_prep_kernel(
    const int* __restrict__ ei, int* __restrict__ cnt,
    const float* __restrict__ x, unsigned* __restrict__ xbf,
    const float* __restrict__ Wl1, const float* __restrict__ Wr1,
    const float* __restrict__ bl1, const float* __restrict__ br1,
    unsigned short* __restrict__ Bt1, float* __restrict__ bc1,
    const float* __restrict__ Wl2, const float* __restrict__ Wr2,
    const float* __restrict__ bl2, const float* __restrict__ br2,
    unsigned short* __restrict__ Bt2, float* __restrict__ bc2,
    const float* __restrict__ bias1, const float* __restrict__ bias2,
    float* __restrict__ bsum1, float* __restrict__ bsum2,
    const float* __restrict__ att1, const float* __restrict__ att2,
    float* __restrict__ attP1, float* __restrict__ attP2)
{
    int b = blockIdx.x;
    int tid = threadIdx.x;
    if (b < CNT_B) {
        int idx = b * 256 + tid;
        if (idx >= NTOT) return;
        int bin;
        if (idx < R_REL * E_EDGES) {
            int r = idx / E_EDGES, e = idx - r * E_EDGES;
            bin = r * N_NODES + ei[(size_t)r * 2 * E_EDGES + E_EDGES + e];
        } else {
            bin = idx - R_REL * E_EDGES;   // self-loop
        }
        atomicAdd(&cnt[bin], 1);
    } else if (b < CNT_B + CVT_B) {
        int i = (b - CNT_B) * 256 + tid;
        if (i >= N_NODES * 16) return;
        float2 v = *(const float2*)(x + 2 * i);
        xbf[i] = f2bfbits(v.x) | (f2bfbits(v.y) << 16);
    } else if (b < CNT_B + CVT_B + P1_B) {
        prep_w_body(Wl1, Wr1, bl1, br1, Bt1, bc1, 32, (b - CNT_B - CVT_B) * 256 + tid);
    } else if (b < CNT_B + CVT_B + P1_B + P2_B) {
        prep_w_body(Wl2, Wr2, bl2, br2, Bt2, bc2, 128, (b - CNT_B - CVT_B - P1_B) * 256 + tid);
    } else {
        // att prescale: leaky folded as att*leaky(t) = (0.6 att) t + (0.4 att)|t|,
        // with log2(e) folded so the edge kernel uses exp2 directly.
        const float L2E = 1.4426950408889634f;
        for (int r = 0; r < R_REL; r++) {
            float a1 = att1[r * 256 + tid];
            float a2 = att2[r * 256 + tid];
            attP1[r * 512 + tid]       = 0.6f * L2E * a1;
            attP1[r * 512 + 256 + tid] = 0.4f * L2E * a1;
            attP2[r * 512 + tid]       = 0.6f * L2E * a2;
            attP2[r * 512 + 256 + tid] = 0.4f * L2E * a2;
        }
        if (tid < 128) {
            float s1 = 0.f, s2 = 0.f;
            for (int r = 0; r < R_REL; r++) { s1 += bias1[r * 128 + tid]; s2 += bias2[r * 128 + tid]; }
            bsum1[tid] = s1; bsum2[tid] = s2;   // consumed by gat6_ln (deferred bias add)
        }
    }
}

// ---------------- CSR build: scan level 1 (per-256 block) ----------------
__global__ __launch_bounds__(256) void scan1_kernel(
    const int* __restrict__ cnt, int* __restrict__ part, int* __restrict__ bsum)
{
    int i = blockIdx.x * 256 + threadIdx.x;
    int v = (i < NB) ? cnt[i] : 0;
    int lane = threadIdx.x & 63, w = threadIdx.x >> 6;
    int x = v;
#pragma unroll
    for (int off = 1; off < 64; off <<= 1) {
        int y = __shfl_up(x, off, 64);
        if (lane >= off) x += y;
    }
    __shared__ int ws[4];
    if (lane == 63) ws[w] = x;
    __syncthreads();
    int add = 0;
    for (int j = 0; j < w; j++) add += ws[j];
    int incl = x + add;
    if (i < NB) part[i] = incl - v;           // exclusive within block
    if (threadIdx.x == 255) bsum[blockIdx.x] = incl;
}

// ---------------- CSR build: scan level 2 ----------------
__global__ __launch_bounds__(256) void scan2_kernel(
    const int* __restrict__ bsum, int* __restrict__ boff)
{
    __shared__ int ws[4];
    int t = threadIdx.x;
    int lane = t & 63, w = t >> 6;
    int base4 = t * 4;
    int pre[4];
    int s = 0;
#pragma unroll
    for (int j = 0; j < 4; j++) {
        int i = base4 + j;
        int x = (i < NBLK) ? bsum[i] : 0;
        pre[j] = s;
        s += x;
    }
    int incl = s;
#pragma unroll
    for (int off = 1; off < 64; off <<= 1) {
        int y = __shfl_up(incl, off, 64);
        if (lane >= off) incl += y;
    }
    if (lane == 63) ws[w] = incl;
    __syncthreads();
    int wbase = 0;
    for (int j = 0; j < w; j++) wbase += ws[j];
    int tbase = wbase + incl - s;
#pragma unroll
    for (int j = 0; j < 4; j++) {
        int i = base4 + j;
        if (i < NBLK) boff[i] = tbase + pre[j];
    }
}

// ---------------- CSR build: finalize rowptr + cursor ----------------
__global__ __launch_bounds__(256) void scan3_kernel(
    const int* __restrict__ part, const int* __restrict__ boff,
    int* __restrict__ rowptr, int* __restrict__ cursor)
{
    int i = blockIdx.x * 256 + threadIdx.x;
    if (i < NB) {
        int v = part[i] + boff[i >> 8];
        rowptr[i] = v;
        cursor[i] = v;
    }
    if (i == 0) rowptr[NB] = NTOT;
}

// ---------------- CSR build: scatter (edges + self-loops) ----------------
__global__ __launch_bounds__(256) void scatter_kernel(
    const int* __restrict__ ei, int* __restrict__ cursor, int* __restrict__ csr)
{
    int idx = blockIdx.x * 256 + threadIdx.x;
    if (idx >= NTOT) return;
    int bin, src;
    if (idx < R_REL * E_EDGES) {
        int r = idx / E_EDGES, e = idx - r * E_EDGES;
        src = ei[(size_t)r * 2 * E_EDGES + e];
        bin = r * N_NODES + ei[(size_t)r * 2 * E_EDGES + E_EDGES + e];
    } else {
        bin = idx - R_REL * E_EDGES;
        src = bin % N_NODES;
    }
    int pos = atomicAdd(&cursor[bin], 1);
    csr[pos] = src;
}

// ---------------- MFMA GEMM (round-12 verified kernel, unchanged) -------------
template <int K>
__global__ __launch_bounds__(256, 4) void gemm_mfma_kernel(
    const unsigned short* __restrict__ A,
    const unsigned short* __restrict__ BtAll,   // [R][512][K] bf16 (n-major)
    const float* __restrict__ biasAll,          // [R][512]
    unsigned short* __restrict__ CAll)          // [R][40000][512]
{
    constexpr int KC = (K > 64) ? 64 : K;
    constexpr int NCH = K / KC;
    constexpr int CH = KC / 8;
    constexpr int TB = 128 * KC * 2;
    __shared__ char lds[2 * TB];
    char* ldsA = lds;
    char* ldsB = lds + TB;

    int tid = threadIdx.x;
    int lane = tid & 63, wave = tid >> 6;
    int l16 = lane & 15, quad = lane >> 4;
    int wm = (wave >> 1) * 64, wn = (wave & 1) * 64;
    int ny = blockIdx.x & 3, z = blockIdx.x >> 2;
    int m0 = blockIdx.y * 128, n0 = ny * 128;

    auto SW = [](int row) { return (KC == 64) ? (row & 7) : ((row >> 1) & 3); };

    const char* Bt = (const char*)(BtAll + (size_t)z * 512 * K);

    f32x4 acc[4][4];
#pragma unroll
    for (int i = 0; i < 4; i++)
#pragma unroll
        for (int j = 0; j < 4; j++) {
            acc[i][j][0] = 0.f; acc[i][j][1] = 0.f;
            acc[i][j][2] = 0.f; acc[i][j][3] = 0.f;
        }

    for (int nc = 0; nc < NCH; ++nc) {
        if (nc) __syncthreads();
#pragma unroll
        for (int it = 0; it < (128 * CH) / 256; ++it) {
            int s = it * 256 + tid;
            int row = s / CH, sc = s % CH;
            int c = sc ^ SW(row);
            int gr = m0 + row; gr = gr < N_NODES ? gr : N_NODES - 1;
            const char* gpA = (const char*)A + (size_t)gr * (K * 2) + nc * KC * 2 + c * 16;
            __builtin_amdgcn_global_load_lds(
                (const __attribute__((address_space(1))) void*)gpA,
                (__attribute__((address_space(3))) void*)(ldsA + it * 4096 + wave * 1024), 16, 0, 0);
            const char* gpB = Bt + (size_t)(n0 + row) * (K * 2) + nc * KC * 2 + c * 16;
            __builtin_amdgcn_global_load_lds(
                (const __attribute__((address_space(1))) void*)gpB,
                (__attribute__((address_space(3))) void*)(ldsB + it * 4096 + wave * 1024), 16, 0, 0);
        }
        __syncthreads();

#pragma unroll
        for (int kk = 0; kk < KC / 32; ++kk) {
            bf16x8 af[4], bfr[4];
#pragma unroll
            for (int i = 0; i < 4; ++i) {
                int row = wm + i * 16 + l16;
                int slot = (kk * 4 + quad) ^ SW(row);
                af[i] = *(const bf16x8*)(ldsA + row * (KC * 2) + slot * 16);
            }
#pragma unroll
            for (int j = 0; j < 4; ++j) {
                int row = wn + j * 16 + l16;
                int slot = (kk * 4 + quad) ^ SW(row);
                bfr[j] = *(const bf16x8*)(ldsB + row * (KC * 2) + slot * 16);
            }
#pragma unroll
            for (int i = 0; i < 4; i++)
#pragma unroll
                for (int j = 0; j < 4; j++)
                    acc[i][j] = __builtin_amdgcn_mfma_f32_16x16x32_bf16(af[i], bfr[j], acc[i][j], 0, 0, 0);
        }
    }

    const float* bias = biasAll + z * 512;
    unsigned short* C = CAll + (size_t)z * N_NODES * 512;
    float biasj[4];
#pragma unroll
    for (int j = 0; j < 4; ++j) biasj[j] = bias[n0 + wn + j * 16 + l16];
#pragma unroll
    for (int i = 0; i < 4; i++) {
        int gr0 = m0 + wm + i * 16 + quad * 4;
#pragma unroll
        for (int j = 0; j < 4; j++) {
            int col = n0 + wn + j * 16 + l16;
#pragma unroll
            for (int rg = 0; rg < 4; rg++) {
                float a = acc[i][j][rg] + biasj[j];
                float b = __shfl_xor(a, 1);
                int grow = gr0 + rg;
                if (!(lane & 1) && grow < N_NODES) {
                    __hip_bfloat162 h2 = __float22bfloat162_rn(make_float2(a, b));
                    unsigned u;
                    __builtin_memcpy(&u, &h2, 4);
                    *(unsigned*)((char*)C + ((size_t)grow * 512 + col) * 2) = u;
                }
            }
        }
    }
}

// ------- fused 6-relation GATv2 + relation-sum + tanh + LayerNorm, CSR --------
// r18: r5 edge-loop body (verified) + 6x unrolled relation bodies with ALL 12
//  rowptr loads issued at kernel entry (parallel chains -> SGPR bounds, zero
//  VGPR growth; xr/att loads stay inside each body to avoid r1's VGPR bloat)
__device__ __forceinline__ void do_rel(
    const char* __restrict__ base,   // lanep + r*RS (src gather base)
    const char* __restrict__ xrp,    // xrbase + r*RS (dst xr slot)
    const float* __restrict__ attL,  // attP + r*512 + lane*4
    const int* __restrict__ csr, int beg, int end,
    float& tot0, float& tot1, float& tot2, float& tot3)
{
    uint2 xru = *(const uint2*)xrp;
    float4 a6 = *(const float4*)attL;
    float4 a4 = *(const float4*)(attL + 256);
    float xr0 = bflo(xru.x), xr1 = bfhi(xru.x), xr2 = bflo(xru.y), xr3 = bfhi(xru.y);

    float sA = 0.f, a0 = 0.f, a1 = 0.f, a2 = 0.f, a3 = 0.f;
    float sB = 0.f, b0 = 0.f, b1 = 0.f, b2 = 0.f, b3 = 0.f;
    int i = beg;
    for (; i + 2 <= end; i += 2) {
        int s0 = csr[i], s1 = csr[i + 1];
        const unsigned* pA = (const unsigned*)(base + ((size_t)(unsigned)s0 << 10));
        const unsigned* pB = (const unsigned*)(base + ((size_t)(unsigned)s1 << 10));
        unsigned uA0 = pA[0], uA1 = pA[1];
        unsigned uB0 = pB[0], uB1 = pB[1];
        float xA0 = bflo(uA0), xA1 = bfhi(uA0), xA2 = bflo(uA1), xA3 = bfhi(uA1);
        float xB0 = bflo(uB0), xB1 = bfhi(uB0), xB2 = bflo(uB1), xB3 = bfhi(uB1);
        float tA0 = xA0 + xr0, tA1 = xA1 + xr1, tA2 = xA2 + xr2, tA3 = xA3 + xr3;
        float tB0 = xB0 + xr0, tB1 = xB1 + xr1, tB2 = xB2 + xr2, tB3 = xB3 + xr3;
        float pa = xA0 * a6.x;
        float pb = xB0 * a6.x;
        pa = fmaf(xA1, a6.y, pa);
        pb = fmaf(xB1, a6.y, pb);
        pa = fmaf(xA2, a6.z, pa);
        pb = fmaf(xB2, a6.z, pb);
        pa = fmaf(xA3, a6.w, pa);
        pb = fmaf(xB3, a6.w, pb);
        pa = fmaf(__builtin_fabsf(tA0), a4.x, pa);
        pb = fmaf(__builtin_fabsf(tB0), a4.x, pb);
        pa = fmaf(__builtin_fabsf(tA1), a4.y, pa);
        pb = fmaf(__builtin_fabsf(tB1), a4.y, pb);
        pa = fmaf(__builtin_fabsf(tA2), a4.z, pa);
        pb = fmaf(__builtin_fabsf(tB2), a4.z, pb);
        pa = fmaf(__builtin_fabsf(tA3), a4.w, pa);
        pb = fmaf(__builtin_fabsf(tB3), a4.w, pb);
        pa = halfsum32(pa);
        pb = halfsum32(pb);
        float wa = __builtin_amdgcn_exp2f(fminf(pa, 120.f));
        float wb = __builtin_amdgcn_exp2f(fminf(pb, 120.f));
        sA += wa; sB += wb;
        a0 = fmaf(wa, xA0, a0); b0 = fmaf(wb, xB0, b0);
        a1 = fmaf(wa, xA1, a1); b1 = fmaf(wb, xB1, b1);
        a2 = fmaf(wa, xA2, a2); b2 = fmaf(wb, xB2, b2);
        a3 = fmaf(wa, xA3, a3); b3 = fmaf(wb, xB3, b3);
    }
    if (i < end) {
        int s0 = csr[i];
        const unsigned* pA = (const unsigned*)(base + ((size_t)(unsigned)s0 << 10));
        unsigned uA0 = pA[0], uA1 = pA[1];
        float xA0 = bflo(uA0), xA1 = bfhi(uA0), xA2 = bflo(uA1), xA3 = bfhi(uA1);
        float tA0 = xA0 + xr0, tA1 = xA1 + xr1, tA2 = xA2 + xr2, tA3 = xA3 + xr3;
        float pa = xA0 * a6.x;
        pa = fmaf(xA1, a6.y, pa);
        pa = fmaf(xA2, a6.z, pa);
        pa = fmaf(xA3, a6.w, pa);
        pa = fmaf(__builtin_fabsf(tA0), a4.x, pa);
        pa = fmaf(__builtin_fabsf(tA1), a4.y, pa);
        pa = fmaf(__builtin_fabsf(tA2), a4.z, pa);
        pa = fmaf(__builtin_fabsf(tA3), a4.w, pa);
        pa = halfsum32(pa);
        float wa = __builtin_amdgcn_exp2f(fminf(pa, 120.f));
        sA += wa;
        a0 = fmaf(wa, xA0, a0);
        a1 = fmaf(wa, xA1, a1);
        a2 = fmaf(wa, xA2, a2);
        a3 = fmaf(wa, xA3, a3);
    }
    sA += sB; a0 += b0; a1 += b1; a2 += b2; a3 += b3;
    float rs = 0.5f * __builtin_amdgcn_rcpf(sA);   // fold head-mean 0.5
    tot0 = fmaf(a0, rs, tot0);
    tot1 = fmaf(a1, rs, tot1);
    tot2 = fmaf(a2, rs, tot2);
    tot3 = fmaf(a3, rs, tot3);
}

__global__ __launch_bounds__(256) void gat6_ln_kernel(
    const unsigned short* __restrict__ XLR,
    const int* __restrict__ rowptr,   // [R*N+1], self-loops included
    const int* __restrict__ csr,      // [NTOT] src indices
    const float* __restrict__ attP,   // [R][2][256]: (0.6*l2e*att | 0.4*l2e*att)
    const float* __restrict__ bsum,   // [128] = sum_r bias[r][ch]
    const float* __restrict__ lng, const float* __restrict__ lnb,
    unsigned* __restrict__ hout)      // [N][64] packed bf16 pairs
{
    int gtid = blockIdx.x * 256 + threadIdx.x;
    int d = gtid >> 6;
    int lane = threadIdx.x & 63;
    if (d >= N_NODES) return;
    int hl = lane & 31;

    const size_t RS = (size_t)N_NODES * 1024;
    const char* lanep = (const char*)XLR + lane * 8;
    const char* xrbase = lanep + ((size_t)(unsigned)d << 10) + 512;
    const float* attL = attP + lane * 4;

    // ---- issue ALL 12 rowptr loads upfront (independent; SGPR bounds) ----
    const int* rp = rowptr + d;
    int tb0 = rp[0 * N_NODES], te0 = rp[0 * N_NODES + 1];
    int tb1 = rp[1 * N_NODES], te1 = rp[1 * N_NODES + 1];
    int tb2 = rp[2 * N_NODES], te2 = rp[2 * N_NODES + 1];
    int tb3 = rp[3 * N_NODES], te3 = rp[3 * N_NODES + 1];
    int tb4 = rp[4 * N_NODES], te4 = rp[4 * N_NODES + 1];
    int tb5 = rp[5 * N_NODES], te5 = rp[5 * N_NODES + 1];
    int b0 = __builtin_amdgcn_readfirstlane(tb0), e0 = __builtin_amdgcn_readfirstlane(te0);
    int b1 = __builtin_amdgcn_readfirstlane(tb1), e1 = __builtin_amdgcn_readfirstlane(te1);
    int b2 = __builtin_amdgcn_readfirstlane(tb2), e2 = __builtin_amdgcn_readfirstlane(te2);
    int b3 = __builtin_amdgcn_readfirstlane(tb3), e3 = __builtin_amdgcn_readfirstlane(te3);
    int b4 = __builtin_amdgcn_readfirstlane(tb4), e4 = __builtin_amdgcn_readfirstlane(te4);
    int b5 = __builtin_amdgcn_readfirstlane(tb5), e5 = __builtin_amdgcn_readfirstlane(te5);

    float tot0 = 0.f, tot1 = 0.f, tot2 = 0.f, tot3 = 0.f;
    do_rel(lanep,          xrbase,          attL,        csr, b0, e0, tot0, tot1, tot2, tot3);
    do_rel(lanep + RS,     xrbase + RS,     attL + 512,  csr, b1, e1, tot0, tot1, tot2, tot3);
    do_rel(lanep + 2 * RS, xrbase + 2 * RS, attL + 1024, csr, b2, e2, tot0, tot1, tot2, tot3);
    do_rel(lanep + 3 * RS, xrbase + 3 * RS, attL + 1536, csr, b3, e3, tot0, tot1, tot2, tot3);
    do_rel(lanep + 4 * RS, xrbase + 4 * RS, attL + 2048, csr, b4, e4, tot0, tot1, tot2, tot3);
    do_rel(lanep + 5 * RS, xrbase + 5 * RS, attL + 2560, csr, b5, e5, tot0, tot1, tot2, tot3);

    // deferred cross-head combine (one swizzle set instead of per-relation)
    tot0 += __shfl_xor(tot0, 32);
    tot1 += __shfl_xor(tot1, 32);
    tot2 += __shfl_xor(tot2, 32);
    tot3 += __shfl_xor(tot3, 32);
    // deferred bias: bsum[ch] = sum_r bias[r][ch] (precomputed in fused_prep)
    float4 bs = *(const float4*)(bsum + hl * 4);

    // tanh + layernorm (128 ch replicated in each 32-lane half)
    float v0 = fast_tanh(tot0 + bs.x);
    float v1 = fast_tanh(tot1 + bs.y);
    float v2 = fast_tanh(tot2 + bs.z);
    float v3 = fast_tanh(tot3 + bs.w);
    float sum = halfsum32(v0 + v1 + v2 + v3);
    float sq = halfsum32(v0 * v0 + v1 * v1 + v2 * v2 + v3 * v3);
    float mean = sum * (1.f / 128.f);
    float var = sq * (1.f / 128.f) - mean * mean;
    float rstd = rsqrtf(var + 1e-5f);
    float4 gg = *(const float4*)(lng + hl * 4);
    float4 bb = *(const float4*)(lnb + hl * 4);
    float o0 = (v0 - mean) * rstd * gg.x + bb.x;
    float o1 = (v1 - mean) * rstd * gg.y + bb.y;
    float o2 = (v2 - mean) * rstd * gg.z + bb.z;
    float o3 = (v3 - mean) * rstd * gg.w + bb.w;
    if (lane < 32) {
        uint2 q;
        q.x = f2bfbits(o0) | (f2bfbits(o1) << 16);
        q.y = f2bfbits(o2) | (f2bfbits(o3) << 16);
        *((uint2*)(hout + (size_t)d * 64) + hl) = q;
    }
}

// ---------------- fused attention pooling + projection ----------------
__global__ __launch_bounds__(256) void pool_proj_kernel(
    const unsigned* __restrict__ hb, const float* __restrict__ query,
    const float* __restrict__ W, const float* __restrict__ pb,
    float* __restrict__ out)
{
    __shared__ float gL[4][128];
    int wave = threadIdx.x >> 6;
    int lane = threadIdx.x & 63;
    int bg = blockIdx.x * 4 + wave;          // grid exact: bg < 2000 always
    float2 q = *(const float2*)(query + 2 * lane);
    float mx = -1e30f, ssum = 0.f, g0 = 0.f, g1 = 0.f;
    for (int i = 0; i < NODES_PER_G; i++) {
        unsigned u = hb[(size_t)(bg * NODES_PER_G + i) * 64 + lane];
        float h0 = bflo(u), h1 = bfhi(u);
        float p = h0 * q.x + h1 * q.y;
#pragma unroll
        for (int off = 32; off >= 1; off >>= 1) p += __shfl_xor(p, off, 64);
        float mn = fmaxf(mx, p);
        float sc = __expf(mx - mn), w = __expf(p - mn);
        ssum = ssum * sc + w;
        g0 = g0 * sc + w * h0;
        g1 = g1 * sc + w * h1;
        mx = mn;
    }
    float inv = 1.f / ssum;
    gL[wave][2 * lane] = g0 * inv;
    gL[wave][2 * lane + 1] = g1 * inv;
    __syncthreads();
    int o0 = lane, o1 = lane + 64;
    float a0 = pb[o0], a1 = pb[o1];
    for (int k = 0; k < 128; k++) {
        float gk = gL[wave][k];
        a0 = fmaf(gk, W[k * 128 + o0], a0);
        a1 = fmaf(gk, W[k * 128 + o1], a1);
    }
    out[(size_t)bg * 128 + o0] = a0;
    out[(size_t)bg * 128 + o1] = a1;
}

extern "C" void kernel_launch(void* const* d_in, const int* in_sizes, int n_in,
                              void* d_out, int out_size, void* d_ws, size_t ws_size,
                              hipStream_t stream)
{
    const float* x     = (const float*)d_in[0];
    const int*   ei    = (const int*)d_in[1];
    const float* Wl1   = (const float*)d_in[3];
    const float* bl1   = (const float*)d_in[4];
    const float* Wr1   = (const float*)d_in[5];
    const float* br1   = (const float*)d_in[6];
    const float* att1  = (const float*)d_in[7];
    const float* bias1 = (const float*)d_in[8];
    const float* Wl2   = (const float*)d_in[9];
    const float* bl2   = (const float*)d_in[10];
    const float* Wr2   = (const float*)d_in[11];
    const float* br2   = (const float*)d_in[12];
    const float* att2  = (const float*)d_in[13];
    const float* bias2 = (const float*)d_in[14];
    const float* ln1g  = (const float*)d_in[15];
    const float* ln1b  = (const float*)d_in[16];
    const float* ln2g  = (const float*)d_in[17];
    const float* ln2b  = (const float*)d_in[18];
    const float* query = (const float*)d_in[19];
    const float* projW = (const float*)d_in[20];
    const float* projb = (const float*)d_in[21];
    float* out = (float*)d_out;

    // workspace layout — all regions rewritten every call
    unsigned short* xlr6 = (unsigned short*)d_ws;                 // 245.76 MB
    unsigned short* h1bf = xlr6 + (size_t)R_REL * N_NODES * 512;  // 10.24 MB
    unsigned short* xbf  = h1bf + (size_t)N_NODES * 128;          // 2.56 MB
    unsigned short* Bt1  = xbf + (size_t)N_NODES * 32;
    unsigned short* Bt2  = Bt1 + R_REL * 512 * 32;
    float* bc1  = (float*)(Bt2 + R_REL * 512 * 128);
    float* bc2  = bc1 + R_REL * 512;
    float* bsum1 = bc2 + R_REL * 512;                             // 128 f32
    float* bsum2 = bsum1 + 128;                                   // 128 f32
    float* attP1 = bsum2 + 128;                                   // R*512 f32
    float* attP2 = attP1 + R_REL * 512;                           // R*512 f32
    int* cnt    = (int*)(attP2 + R_REL * 512);                    // NB
    int* part   = cnt + NB;                                       // NB
    int* rowptr = part + NB;                                      // NB+1
    int* cursor = rowptr + NB + 1;                                // NB
    int* bsum   = cursor + NB;                                    // NBLK
    int* boff   = bsum + NBLK;                                    // NBLK
    int* csr    = boff + NBLK;                                    // NTOT

    // ---- CSR build + prep (fused) ----
    hipMemsetAsync(cnt, 0, sizeof(int) * NB, stream);
    fused_prep_kernel<<<PREP_TOTAL, 256, 0, stream>>>(
        ei, cnt, x, (unsigned*)xbf,
        Wl1, Wr1, bl1, br1, Bt1, bc1,
        Wl2, Wr2, bl2, br2, Bt2, bc2,
        bias1, bias2, bsum1, bsum2,
        att1, att2, attP1, attP2);
    scan1_kernel<<<NBLK, 256, 0, stream>>>(cnt, part, bsum);
    scan2_kernel<<<1, 256, 0, stream>>>(bsum, boff);
    scan3_kernel<<<NBLK, 256, 0, stream>>>(part, boff, rowptr, cursor);
    scatter_kernel<<<(NTOT + 255) / 256, 256, 0, stream>>>(ei, cursor, csr);

    dim3 ggrid(24, (N_NODES + 127) / 128, 1);   // x = z*4+ny (same-m adjacent), y = m-tile
    // ---- layer 1 ----
    gemm_mfma_kernel<32><<<ggrid, 256, 0, stream>>>(xbf, Bt1, bc1, xlr6);
    gat6_ln_kernel<<<N_NODES / 4, 256, 0, stream>>>(
        xlr6, rowptr, csr, attP1, bsum1, ln1g, ln1b, (unsigned*)h1bf);
    // ---- layer 2 ----
    gemm_mfma_kernel<128><<<ggrid, 256, 0, stream>>>(h1bf, Bt2, bc2, xlr6);
    gat6_ln_kernel<<<N_NODES / 4, 256, 0, stream>>>(
        xlr6, rowptr, csr, attP2, bsum2, ln2g, ln2b, (unsigned*)h1bf);
    // ---- pooling + projection (fused) ----
    pool_proj_kernel<<<B_GRAPHS / 4, 256, 0, stream>>>(
        (unsigned*)h1bf, query, projW, projb, out);
}

// Round 7
// 399.503 us; speedup vs baseline: 1.1944x; 1.1944x over previous
//
#include <hip/hip_runtime.h>
#include <hip/hip_bf16.h>
#include <math.h>

#define N_NODES 40000
#define E_EDGES 60000
#define R_REL 6
#define IN_F 32
#define HID_F 128
#define B_GRAPHS 2000
#define NODES_PER_G 20
#define NEG_SLOPE 0.2f
#define NB (R_REL * N_NODES)            // 240000 bins
#define NREAL (R_REL * E_EDGES)         // 360000 real edges (self-loops analytic)
#define NBLK ((NB + 255) / 256)         // 938 scan blocks

// fused-prep block ranges
#define CNT_B ((NREAL + 255) / 256)         // 1407
#define CVT_B ((N_NODES * 16 + 255) / 256)  // 2500
#define P1_B  (R_REL * 512 * 32 / 256)      // 384
#define P2_B  (R_REL * 512 * 128 / 256)     // 1536
#define PREP_TOTAL (CNT_B + CVT_B + P1_B + P2_B + 1)

typedef __bf16 bf16x8 __attribute__((ext_vector_type(8)));
typedef float f32x4 __attribute__((ext_vector_type(4)));

__device__ __forceinline__ unsigned f2bfbits(float f) {
    unsigned u = __builtin_bit_cast(unsigned, f);
    return (u + 0x7FFFu + ((u >> 16) & 1u)) >> 16;   // RNE
}
__device__ __forceinline__ float bflo(unsigned u) { return __builtin_bit_cast(float, u << 16); }
__device__ __forceinline__ float bfhi(unsigned u) { return __builtin_bit_cast(float, u & 0xFFFF0000u); }

// tanh(x) = 1 - 2/(e^{2x}+1), via hw exp2 + fast rcp (~1e-6 rel, saturates to +-1)
__device__ __forceinline__ float fast_tanh(float x) {
    float e = __builtin_amdgcn_exp2f(x * 2.8853900817779268f);   // e^{2x}
    return fmaf(-2.f, __builtin_amdgcn_rcpf(e + 1.f), 1.f);
}

// DPP rotation add within row-16: pure VALU, no LDS pipe (verified r4/r5)
template<int CTRL>
__device__ __forceinline__ float dppadd(float v) {
    int m = __builtin_amdgcn_update_dpp(0, __builtin_bit_cast(int, v), CTRL, 0xF, 0xF, true);
    return v + __builtin_bit_cast(float, m);
}
__device__ __forceinline__ float rowsum16(float v) {   // all 16 lanes get row sum
    v = dppadd<0x121>(v);   // row_ror:1
    v = dppadd<0x122>(v);   // row_ror:2
    v = dppadd<0x124>(v);   // row_ror:4
    v = dppadd<0x128>(v);   // row_ror:8
    return v;
}
__device__ __forceinline__ float halfsum32(float v) {  // full sum within each 32-lane half
    v += __shfl_xor(v, 16);
    return rowsum16(v);
}

__device__ __forceinline__ void prep_w_body(
    const float* __restrict__ Wl, const float* __restrict__ Wr,
    const float* __restrict__ bl, const float* __restrict__ br,
    unsigned short* __restrict__ Bt, float* __restrict__ bcat, int K, int idx)
{
    if (idx >= R_REL * 512 * K) return;
    int k = idx % K;
    int rn = idx / K;
    int n = rn % 512;
    int r = rn / 512;
    int nn = n & 255;
    const float* W = (n < 256) ? Wl : Wr;
    float w = W[((size_t)r * K + k) * 256 + nn];
    Bt[idx] = (unsigned short)f2bfbits(w);
    if (k == 0)
        bcat[rn] = (n < 256) ? bl[r * 256 + nn] : br[r * 256 + nn];
}

// -------- fused prep: count + cvt + prep_w x2 + bias_sum + att-prescale -------
__global__ __launch_bounds__(256) void fused_prep_kernel(
    const int* __restrict__ ei, int* __restrict__ cnt,
    const float* __restrict__ x, unsigned* __restrict__ xbf,
    const float* __restrict__ Wl1, const float* __restrict__ Wr1,
    const float* __restrict__ bl1, const float* __restrict__ br1,
    unsigned short* __restrict__ Bt1, float* __restrict__ bc1,
    const float* __restrict__ Wl2, const float* __restrict__ Wr2,
    const float* __restrict__ bl2, const float* __restrict__ br2,
    unsigned short* __restrict__ Bt2, float* __restrict__ bc2,
    const float* __restrict__ bias1, const float* __restrict__ bias2,
    float* __restrict__ bsum1, float* __restrict__ bsum2,
    const float* __restrict__ att1, const float* __restrict__ att2,
    float* __restrict__ attP1, float* __restrict__ attP2)
{
    int b = blockIdx.x;
    int tid = threadIdx.x;
    if (b < CNT_B) {
        int idx = b * 256 + tid;
        if (idx >= NREAL) return;
        int r = idx / E_EDGES, e = idx - r * E_EDGES;
        int bin = r * N_NODES + ei[(size_t)r * 2 * E_EDGES + E_EDGES + e];
        atomicAdd(&cnt[bin], 1);
    } else if (b < CNT_B + CVT_B) {
        int i = (b - CNT_B) * 256 + tid;
        if (i >= N_NODES * 16) return;
        float2 v = *(const float2*)(x + 2 * i);
        xbf[i] = f2bfbits(v.x) | (f2bfbits(v.y) << 16);
    } else if (b < CNT_B + CVT_B + P1_B) {
        prep_w_body(Wl1, Wr1, bl1, br1, Bt1, bc1, 32, (b - CNT_B - CVT_B) * 256 + tid);
    } else if (b < CNT_B + CVT_B + P1_B + P2_B) {
        prep_w_body(Wl2, Wr2, bl2, br2, Bt2, bc2, 128, (b - CNT_B - CVT_B - P1_B) * 256 + tid);
    } else {
        // att prescale: leaky folded as att*leaky(t) = (0.6 att) t + (0.4 att)|t|,
        // with log2(e) folded so the edge kernel uses exp2 directly.
        const float L2E = 1.4426950408889634f;
        for (int r = 0; r < R_REL; r++) {
            float a1 = att1[r * 256 + tid];
            float a2 = att2[r * 256 + tid];
            attP1[r * 512 + tid]       = 0.6f * L2E * a1;
            attP1[r * 512 + 256 + tid] = 0.4f * L2E * a1;
            attP2[r * 512 + tid]       = 0.6f * L2E * a2;
            attP2[r * 512 + 256 + tid] = 0.4f * L2E * a2;
        }
        if (tid < 128) {
            float s1 = 0.f, s2 = 0.f;
            for (int r = 0; r < R_REL; r++) { s1 += bias1[r * 128 + tid]; s2 += bias2[r * 128 + tid]; }
            bsum1[tid] = s1; bsum2[tid] = s2;   // consumed by gat6_ln (deferred bias add)
        }
    }
}

// ---------------- CSR build: scan level 1 (per-256 block) ----------------
__global__ __launch_bounds__(256) void scan1_kernel(
    const int* __restrict__ cnt, int* __restrict__ part, int* __restrict__ bsum)
{
    int i = blockIdx.x * 256 + threadIdx.x;
    int v = (i < NB) ? cnt[i] : 0;
    int lane = threadIdx.x & 63, w = threadIdx.x >> 6;
    int x = v;
#pragma unroll
    for (int off = 1; off < 64; off <<= 1) {
        int y = __shfl_up(x, off, 64);
        if (lane >= off) x += y;
    }
    __shared__ int ws[4];
    if (lane == 63) ws[w] = x;
    __syncthreads();
    int add = 0;
    for (int j = 0; j < w; j++) add += ws[j];
    int incl = x + add;
    if (i < NB) part[i] = incl - v;           // exclusive within block
    if (threadIdx.x == 255) bsum[blockIdx.x] = incl;
}

// ----- CSR build: finalize rowptr + cursor (scan2 folded in: each block -----
// ----- computes its own offset by a masked parallel reduce over bsum)    -----
__global__ __launch_bounds__(256) void scan3_kernel(
    const int* __restrict__ part, const int* __restrict__ bsum,
    int* __restrict__ rowptr, int* __restrict__ cursor)
{
    __shared__ int ws[4];
    int t = threadIdx.x, b = blockIdx.x;
    int s = 0;
    for (int j = t; j < b; j += 256) s += bsum[j];   // <=4 iters (NBLK=938)
#pragma unroll
    for (int off = 32; off >= 1; off >>= 1) s += __shfl_xor(s, off);
    int lane = t & 63, w = t >> 6;
    if (lane == 0) ws[w] = s;
    __syncthreads();
    int boffb = ws[0] + ws[1] + ws[2] + ws[3];
    int i = b * 256 + t;
    if (i < NB) {
        int v = part[i] + boffb;
        rowptr[i] = v;
        cursor[i] = v;
    }
    if (i == 0) rowptr[NB] = NREAL;
}

// ---------------- CSR build: scatter (real edges only) ----------------
__global__ __launch_bounds__(256) void scatter_kernel(
    const int* __restrict__ ei, int* __restrict__ cursor, int* __restrict__ csr)
{
    int idx = blockIdx.x * 256 + threadIdx.x;
    if (idx >= NREAL) return;
    int r = idx / E_EDGES, e = idx - r * E_EDGES;
    int src = ei[(size_t)r * 2 * E_EDGES + e];
    int bin = r * N_NODES + ei[(size_t)r * 2 * E_EDGES + E_EDGES + e];
    int pos = atomicAdd(&cursor[bin], 1);
    csr[pos] = src;
}

// ---------------- MFMA GEMM (round-12 verified kernel, unchanged) -------------
template <int K>
__global__ __launch_bounds__(256, 4) void gemm_mfma_kernel(
    const unsigned short* __restrict__ A,
    const unsigned short* __restrict__ BtAll,   // [R][512][K] bf16 (n-major)
    const float* __restrict__ biasAll,          // [R][512]
    unsigned short* __restrict__ CAll)          // [R][40000][512]
{
    constexpr int KC = (K > 64) ? 64 : K;
    constexpr int NCH = K / KC;
    constexpr int CH = KC / 8;
    constexpr int TB = 128 * KC * 2;
    __shared__ char lds[2 * TB];
    char* ldsA = lds;
    char* ldsB = lds + TB;

    int tid = threadIdx.x;
    int lane = tid & 63, wave = tid >> 6;
    int l16 = lane & 15, quad = lane >> 4;
    int wm = (wave >> 1) * 64, wn = (wave & 1) * 64;
    int ny = blockIdx.x & 3, z = blockIdx.x >> 2;
    int m0 = blockIdx.y * 128, n0 = ny * 128;

    auto SW = [](int row) { return (KC == 64) ? (row & 7) : ((row >> 1) & 3); };

    const char* Bt = (const char*)(BtAll + (size_t)z * 512 * K);

    f32x4 acc[4][4];
#pragma unroll
    for (int i = 0; i < 4; i++)
#pragma unroll
        for (int j = 0; j < 4; j++) {
            acc[i][j][0] = 0.f; acc[i][j][1] = 0.f;
            acc[i][j][2] = 0.f; acc[i][j][3] = 0.f;
        }

    for (int nc = 0; nc < NCH; ++nc) {
        if (nc) __syncthreads();
#pragma unroll
        for (int it = 0; it < (128 * CH) / 256; ++it) {
            int s = it * 256 + tid;
            int row = s / CH, sc = s % CH;
            int c = sc ^ SW(row);
            int gr = m0 + row; gr = gr < N_NODES ? gr : N_NODES - 1;
            const char* gpA = (const char*)A + (size_t)gr * (K * 2) + nc * KC * 2 + c * 16;
            __builtin_amdgcn_global_load_lds(
                (const __attribute__((address_space(1))) void*)gpA,
                (__attribute__((address_space(3))) void*)(ldsA + it * 4096 + wave * 1024), 16, 0, 0);
            const char* gpB = Bt + (size_t)(n0 + row) * (K * 2) + nc * KC * 2 + c * 16;
            __builtin_amdgcn_global_load_lds(
                (const __attribute__((address_space(1))) void*)gpB,
                (__attribute__((address_space(3))) void*)(ldsB + it * 4096 + wave * 1024), 16, 0, 0);
        }
        __syncthreads();

#pragma unroll
        for (int kk = 0; kk < KC / 32; ++kk) {
            bf16x8 af[4], bfr[4];
#pragma unroll
            for (int i = 0; i < 4; ++i) {
                int row = wm + i * 16 + l16;
                int slot = (kk * 4 + quad) ^ SW(row);
                af[i] = *(const bf16x8*)(ldsA + row * (KC * 2) + slot * 16);
            }
#pragma unroll
            for (int j = 0; j < 4; ++j) {
                int row = wn + j * 16 + l16;
                int slot = (kk * 4 + quad) ^ SW(row);
                bfr[j] = *(const bf16x8*)(ldsB + row * (KC * 2) + slot * 16);
            }
#pragma unroll
            for (int i = 0; i < 4; i++)
#pragma unroll
                for (int j = 0; j < 4; j++)
                    acc[i][j] = __builtin_amdgcn_mfma_f32_16x16x32_bf16(af[i], bfr[j], acc[i][j], 0, 0, 0);
        }
    }

    const float* bias = biasAll + z * 512;
    unsigned short* C = CAll + (size_t)z * N_NODES * 512;
    float biasj[4];
#pragma unroll
    for (int j = 0; j < 4; ++j) biasj[j] = bias[n0 + wn + j * 16 + l16];
#pragma unroll
    for (int i = 0; i < 4; i++) {
        int gr0 = m0 + wm + i * 16 + quad * 4;
#pragma unroll
        for (int j = 0; j < 4; j++) {
            int col = n0 + wn + j * 16 + l16;
#pragma unroll
            for (int rg = 0; rg < 4; rg++) {
                float a = acc[i][j][rg] + biasj[j];
                float b = __shfl_xor(a, 1);
                int grow = gr0 + rg;
                if (!(lane & 1) && grow < N_NODES) {
                    __hip_bfloat162 h2 = __float22bfloat162_rn(make_float2(a, b));
                    unsigned u;
                    __builtin_memcpy(&u, &h2, 4);
                    *(unsigned*)((char*)C + ((size_t)grow * 512 + col) * 2) = u;
                }
            }
        }
    }
}

// ------- fused 6-relation GATv2 + relation-sum + tanh + LayerNorm, CSR --------
// r19: exact r5 structure (rolled loop, lean liveness — r1/r2/r6 proved any
// liveness growth loses more to occupancy than latency overlap gains) +
// self-loops removed from CSR: each relation's accumulators are INITIALIZED
// with the analytic self-edge (src=dst, xl row at xrp-512). Same VALU as the
// loop iteration it replaces; one fewer csr-dependent gather chain.
__global__ __launch_bounds__(256) void gat6_ln_kernel(
    const unsigned short* __restrict__ XLR,
    const int* __restrict__ rowptr,   // [R*N+1], REAL edges only
    const int* __restrict__ csr,      // [NREAL] src indices
    const float* __restrict__ attP,   // [R][2][256]: (0.6*l2e*att | 0.4*l2e*att)
    const float* __restrict__ bsum,   // [128] = sum_r bias[r][ch]
    const float* __restrict__ lng, const float* __restrict__ lnb,
    unsigned* __restrict__ hout)      // [N][64] packed bf16 pairs
{
    int gtid = blockIdx.x * 256 + threadIdx.x;
    int d = gtid >> 6;
    int lane = threadIdx.x & 63;
    if (d >= N_NODES) return;
    int hl = lane & 31;

    const size_t RS = (size_t)N_NODES * 1024;
    const char* lanep = (const char*)XLR + lane * 8;
    const char* xrbase = lanep + ((size_t)(unsigned)d << 10) + 512;

    float tot0 = 0.f, tot1 = 0.f, tot2 = 0.f, tot3 = 0.f;
#pragma unroll 1
    for (int r = 0; r < R_REL; r++) {
        const char* xrp = xrbase + (size_t)r * RS;
        uint2 xru = *(const uint2*)xrp;
        uint2 xls = *(const uint2*)(xrp - 512);   // dst's own xl row (self-loop)
        float4 a6 = *(const float4*)(attP + r * 512 + lane * 4);
        float4 a4 = *(const float4*)(attP + r * 512 + 256 + lane * 4);
        int bin = r * N_NODES + d;
        int beg = __builtin_amdgcn_readfirstlane(rowptr[bin]);
        int end = __builtin_amdgcn_readfirstlane(rowptr[bin + 1]);
        const char* base = lanep + (size_t)r * RS;
        float xr0 = bflo(xru.x), xr1 = bfhi(xru.x), xr2 = bflo(xru.y), xr3 = bfhi(xru.y);

        // ---- analytic self-edge initializes the accumulators ----
        float xS0 = bflo(xls.x), xS1 = bfhi(xls.x), xS2 = bflo(xls.y), xS3 = bfhi(xls.y);
        float tS0 = xS0 + xr0, tS1 = xS1 + xr1, tS2 = xS2 + xr2, tS3 = xS3 + xr3;
        float ps = xS0 * a6.x;
        ps = fmaf(xS1, a6.y, ps);
        ps = fmaf(xS2, a6.z, ps);
        ps = fmaf(xS3, a6.w, ps);
        ps = fmaf(__builtin_fabsf(tS0), a4.x, ps);
        ps = fmaf(__builtin_fabsf(tS1), a4.y, ps);
        ps = fmaf(__builtin_fabsf(tS2), a4.z, ps);
        ps = fmaf(__builtin_fabsf(tS3), a4.w, ps);
        ps = halfsum32(ps);
        float wS = __builtin_amdgcn_exp2f(fminf(ps, 120.f));
        float sA = wS, a0 = wS * xS0, a1 = wS * xS1, a2 = wS * xS2, a3 = wS * xS3;
        float sB = 0.f, b0 = 0.f, b1 = 0.f, b2 = 0.f, b3 = 0.f;
        int i = beg;
        for (; i + 2 <= end; i += 2) {
            int s0 = csr[i], s1 = csr[i + 1];
            const unsigned* pA = (const unsigned*)(base + ((size_t)(unsigned)s0 << 10));
            const unsigned* pB = (const unsigned*)(base + ((size_t)(unsigned)s1 << 10));
            unsigned uA0 = pA[0], uA1 = pA[1];
            unsigned uB0 = pB[0], uB1 = pB[1];
            float xA0 = bflo(uA0), xA1 = bfhi(uA0), xA2 = bflo(uA1), xA3 = bfhi(uA1);
            float xB0 = bflo(uB0), xB1 = bfhi(uB0), xB2 = bflo(uB1), xB3 = bfhi(uB1);
            float tA0 = xA0 + xr0, tA1 = xA1 + xr1, tA2 = xA2 + xr2, tA3 = xA3 + xr3;
            float tB0 = xB0 + xr0, tB1 = xB1 + xr1, tB2 = xB2 + xr2, tB3 = xB3 + xr3;
            float pa = xA0 * a6.x;
            float pb = xB0 * a6.x;
            pa = fmaf(xA1, a6.y, pa);
            pb = fmaf(xB1, a6.y, pb);
            pa = fmaf(xA2, a6.z, pa);
            pb = fmaf(xB2, a6.z, pb);
            pa = fmaf(xA3, a6.w, pa);
            pb = fmaf(xB3, a6.w, pb);
            pa = fmaf(__builtin_fabsf(tA0), a4.x, pa);
            pb = fmaf(__builtin_fabsf(tB0), a4.x, pb);
            pa = fmaf(__builtin_fabsf(tA1), a4.y, pa);
            pb = fmaf(__builtin_fabsf(tB1), a4.y, pb);
            pa = fmaf(__builtin_fabsf(tA2), a4.z, pa);
            pb = fmaf(__builtin_fabsf(tB2), a4.z, pb);
            pa = fmaf(__builtin_fabsf(tA3), a4.w, pa);
            pb = fmaf(__builtin_fabsf(tB3), a4.w, pb);
            pa = halfsum32(pa);
            pb = halfsum32(pb);
            float wa = __builtin_amdgcn_exp2f(fminf(pa, 120.f));
            float wb = __builtin_amdgcn_exp2f(fminf(pb, 120.f));
            sA += wa; sB += wb;
            a0 = fmaf(wa, xA0, a0); b0 = fmaf(wb, xB0, b0);
            a1 = fmaf(wa, xA1, a1); b1 = fmaf(wb, xB1, b1);
            a2 = fmaf(wa, xA2, a2); b2 = fmaf(wb, xB2, b2);
            a3 = fmaf(wa, xA3, a3); b3 = fmaf(wb, xB3, b3);
        }
        if (i < end) {
            int s0 = csr[i];
            const unsigned* pA = (const unsigned*)(base + ((size_t)(unsigned)s0 << 10));
            unsigned uA0 = pA[0], uA1 = pA[1];
            float xA0 = bflo(uA0), xA1 = bfhi(uA0), xA2 = bflo(uA1), xA3 = bfhi(uA1);
            float tA0 = xA0 + xr0, tA1 = xA1 + xr1, tA2 = xA2 + xr2, tA3 = xA3 + xr3;
            float pa = xA0 * a6.x;
            pa = fmaf(xA1, a6.y, pa);
            pa = fmaf(xA2, a6.z, pa);
            pa = fmaf(xA3, a6.w, pa);
            pa = fmaf(__builtin_fabsf(tA0), a4.x, pa);
            pa = fmaf(__builtin_fabsf(tA1), a4.y, pa);
            pa = fmaf(__builtin_fabsf(tA2), a4.z, pa);
            pa = fmaf(__builtin_fabsf(tA3), a4.w, pa);
            pa = halfsum32(pa);
            float wa = __builtin_amdgcn_exp2f(fminf(pa, 120.f));
            sA += wa;
            a0 = fmaf(wa, xA0, a0);
            a1 = fmaf(wa, xA1, a1);
            a2 = fmaf(wa, xA2, a2);
            a3 = fmaf(wa, xA3, a3);
        }
        sA += sB; a0 += b0; a1 += b1; a2 += b2; a3 += b3;
        float rs = 0.5f * __builtin_amdgcn_rcpf(sA);   // fold head-mean 0.5
        tot0 = fmaf(a0, rs, tot0);
        tot1 = fmaf(a1, rs, tot1);
        tot2 = fmaf(a2, rs, tot2);
        tot3 = fmaf(a3, rs, tot3);
    }

    // deferred cross-head combine (one swizzle set instead of per-relation)
    tot0 += __shfl_xor(tot0, 32);
    tot1 += __shfl_xor(tot1, 32);
    tot2 += __shfl_xor(tot2, 32);
    tot3 += __shfl_xor(tot3, 32);
    // deferred bias: bsum[ch] = sum_r bias[r][ch] (precomputed in fused_prep)
    float4 bs = *(const float4*)(bsum + hl * 4);

    // tanh + layernorm (128 ch replicated in each 32-lane half)
    float v0 = fast_tanh(tot0 + bs.x);
    float v1 = fast_tanh(tot1 + bs.y);
    float v2 = fast_tanh(tot2 + bs.z);
    float v3 = fast_tanh(tot3 + bs.w);
    float sum = halfsum32(v0 + v1 + v2 + v3);
    float sq = halfsum32(v0 * v0 + v1 * v1 + v2 * v2 + v3 * v3);
    float mean = sum * (1.f / 128.f);
    float var = sq * (1.f / 128.f) - mean * mean;
    float rstd = rsqrtf(var + 1e-5f);
    float4 gg = *(const float4*)(lng + hl * 4);
    float4 bb = *(const float4*)(lnb + hl * 4);
    float o0 = (v0 - mean) * rstd * gg.x + bb.x;
    float o1 = (v1 - mean) * rstd * gg.y + bb.y;
    float o2 = (v2 - mean) * rstd * gg.z + bb.z;
    float o3 = (v3 - mean) * rstd * gg.w + bb.w;
    if (lane < 32) {
        uint2 q;
        q.x = f2bfbits(o0) | (f2bfbits(o1) << 16);
        q.y = f2bfbits(o2) | (f2bfbits(o3) << 16);
        *((uint2*)(hout + (size_t)d * 64) + hl) = q;
    }
}

// ---------------- fused attention pooling + projection ----------------
__global__ __launch_bounds__(256) void pool_proj_kernel(
    const unsigned* __restrict__ hb, const float* __restrict__ query,
    const float* __restrict__ W, const float* __restrict__ pb,
    float* __restrict__ out)
{
    __shared__ float gL[4][128];
    int wave = threadIdx.x >> 6;
    int lane = threadIdx.x & 63;
    int bg = blockIdx.x * 4 + wave;          // grid exact: bg < 2000 always
    float2 q = *(const float2*)(query + 2 * lane);
    float mx = -1e30f, ssum = 0.f, g0 = 0.f, g1 = 0.f;
    for (int i = 0; i < NODES_PER_G; i++) {
        unsigned u = hb[(size_t)(bg * NODES_PER_G + i) * 64 + lane];
        float h0 = bflo(u), h1 = bfhi(u);
        float p = h0 * q.x + h1 * q.y;
#pragma unroll
        for (int off = 32; off >= 1; off >>= 1) p += __shfl_xor(p, off, 64);
        float mn = fmaxf(mx, p);
        float sc = __expf(mx - mn), w = __expf(p - mn);
        ssum = ssum * sc + w;
        g0 = g0 * sc + w * h0;
        g1 = g1 * sc + w * h1;
        mx = mn;
    }
    float inv = 1.f / ssum;
    gL[wave][2 * lane] = g0 * inv;
    gL[wave][2 * lane + 1] = g1 * inv;
    __syncthreads();
    int o0 = lane, o1 = lane + 64;
    float a0 = pb[o0], a1 = pb[o1];
    for (int k = 0; k < 128; k++) {
        float gk = gL[wave][k];
        a0 = fmaf(gk, W[k * 128 + o0], a0);
        a1 = fmaf(gk, W[k * 128 + o1], a1);
    }
    out[(size_t)bg * 128 + o0] = a0;
    out[(size_t)bg * 128 + o1] = a1;
}

extern "C" void kernel_launch(void* const* d_in, const int* in_sizes, int n_in,
                              void* d_out, int out_size, void* d_ws, size_t ws_size,
                              hipStream_t stream)
{
    const float* x     = (const float*)d_in[0];
    const int*   ei    = (const int*)d_in[1];
    const float* Wl1   = (const float*)d_in[3];
    const float* bl1   = (const float*)d_in[4];
    const float* Wr1   = (const float*)d_in[5];
    const float* br1   = (const float*)d_in[6];
    const float* att1  = (const float*)d_in[7];
    const float* bias1 = (const float*)d_in[8];
    const float* Wl2   = (const float*)d_in[9];
    const float* bl2   = (const float*)d_in[10];
    const float* Wr2   = (const float*)d_in[11];
    const float* br2   = (const float*)d_in[12];
    const float* att2  = (const float*)d_in[13];
    const float* bias2 = (const float*)d_in[14];
    const float* ln1g  = (const float*)d_in[15];
    const float* ln1b  = (const float*)d_in[16];
    const float* ln2g  = (const float*)d_in[17];
    const float* ln2b  = (const float*)d_in[18];
    const float* query = (const float*)d_in[19];
    const float* projW = (const float*)d_in[20];
    const float* projb = (const float*)d_in[21];
    float* out = (float*)d_out;

    // workspace layout — all regions rewritten every call
    unsigned short* xlr6 = (unsigned short*)d_ws;                 // 245.76 MB
    unsigned short* h1bf = xlr6 + (size_t)R_REL * N_NODES * 512;  // 10.24 MB
    unsigned short* xbf  = h1bf + (size_t)N_NODES * 128;          // 2.56 MB
    unsigned short* Bt1  = xbf + (size_t)N_NODES * 32;
    unsigned short* Bt2  = Bt1 + R_REL * 512 * 32;
    float* bc1  = (float*)(Bt2 + R_REL * 512 * 128);
    float* bc2  = bc1 + R_REL * 512;
    float* bsum1 = bc2 + R_REL * 512;                             // 128 f32
    float* bsum2 = bsum1 + 128;                                   // 128 f32
    float* attP1 = bsum2 + 128;                                   // R*512 f32
    float* attP2 = attP1 + R_REL * 512;                           // R*512 f32
    int* cnt    = (int*)(attP2 + R_REL * 512);                    // NB
    int* part   = cnt + NB;                                       // NB
    int* rowptr = part + NB;                                      // NB+1
    int* cursor = rowptr + NB + 1;                                // NB
    int* bsum   = cursor + NB;                                    // NBLK
    int* csr    = bsum + NBLK;                                    // NREAL

    // ---- CSR build + prep (fused) ----
    hipMemsetAsync(cnt, 0, sizeof(int) * NB, stream);
    fused_prep_kernel<<<PREP_TOTAL, 256, 0, stream>>>(
        ei, cnt, x, (unsigned*)xbf,
        Wl1, Wr1, bl1, br1, Bt1, bc1,
        Wl2, Wr2, bl2, br2, Bt2, bc2,
        bias1, bias2, bsum1, bsum2,
        att1, att2, attP1, attP2);
    scan1_kernel<<<NBLK, 256, 0, stream>>>(cnt, part, bsum);
    scan3_kernel<<<NBLK, 256, 0, stream>>>(part, bsum, rowptr, cursor);
    scatter_kernel<<<(NREAL + 255) / 256, 256, 0, stream>>>(ei, cursor, csr);

    dim3 ggrid(24, (N_NODES + 127) / 128, 1);   // x = z*4+ny (same-m adjacent), y = m-tile
    // ---- layer 1 ----
    gemm_mfma_kernel<32><<<ggrid, 256, 0, stream>>>(xbf, Bt1, bc1, xlr6);
    gat6_ln_kernel<<<N_NODES / 4, 256, 0, stream>>>(
        xlr6, rowptr, csr, attP1, bsum1, ln1g, ln1b, (unsigned*)h1bf);
    // ---- layer 2 ----
    gemm_mfma_kernel<128><<<ggrid, 256, 0, stream>>>(h1bf, Bt2, bc2, xlr6);
    gat6_ln_kernel<<<N_NODES / 4, 256, 0, stream>>>(
        xlr6, rowptr, csr, attP2, bsum2, ln2g, ln2b, (unsigned*)h1bf);
    // ---- pooling + projection (fused) ----
    pool_proj_kernel<<<B_GRAPHS / 4, 256, 0, stream>>>(
        (unsigned*)h1bf, query, projW, projb, out);
}